// Round 1
// baseline (540.644 us; speedup 1.0000x reference)
//
#include <hip/hip_runtime.h>
#include <cmath>

namespace {
constexpr float kE   = 3130.0f;
constexpr float kNu  = 0.37f;
constexpr float kSy0 = 64.8f;
constexpr float kH   = 100.0f;
constexpr float kG   = kE / (2.0f * (1.0f + kNu));
constexpr float kLam = kE * kNu / ((1.0f + kNu) * (1.0f - 2.0f * kNu));
constexpr float kC   = kE / ((1.0f + kNu) * (1.0f - 2.0f * kNu));
constexpr float kC11 = kC * (1.0f - kNu);
constexpr float kC12 = kC * kNu;
constexpr float kInv3GH = 1.0f / (3.0f * kG + kH);
constexpr int kS = 2048;   // time steps
constexpr int kT = 8;      // steps batched per reduction
constexpr int kLs = 192;   // latent size
}

// One wave per batch element b (64 lanes = 64 bulk triples).
// Lane k owns h = {3k, 3k+1, 3k+2}. Sequential scan over S in-registers.
__global__ __launch_bounds__(64, 1)
void j2_scan_kernel(const float* __restrict__ x,
                    const float* __restrict__ W1,
                    const float* __restrict__ W2,
                    float* __restrict__ out)
{
    const int b = blockIdx.x;   // 0..127
    const int k = threadIdx.x;  // 0..63

    // ---- per-lane constants -------------------------------------------------
    // W1 rows for this lane's 3 latent components
    float w[3][3];
#pragma unroll
    for (int j = 0; j < 3; ++j)
#pragma unroll
        for (int f = 0; f < 3; ++f)
            w[j][f] = W1[(3 * k + j) * 3 + f];

    // Fold elastic matrix D into the strain projection:
    // sig_tr_j = sig_old_j + dx . e_j  where e_j = sum_m D[j][m] * w[m][:]
    float e0[3], e1[3], e2[3], lv[3];
#pragma unroll
    for (int f = 0; f < 3; ++f) {
        e0[f] = kC11 * w[0][f] + kC12 * w[1][f];
        e1[f] = kC12 * w[0][f] + kC11 * w[1][f];
        e2[f] = kG * w[2][f];
        lv[f] = kLam * (w[0][f] + w[1][f]);
    }

    // softplus(W2) weights for this lane's 3 components
    float sp[3][3];
#pragma unroll
    for (int o = 0; o < 3; ++o)
#pragma unroll
        for (int j = 0; j < 3; ++j) {
            float v = W2[o * kLs + 3 * k + j];
            sp[o][j] = log1pf(expf(v));
        }

    // ---- scan state ---------------------------------------------------------
    float px0 = 0.f, px1 = 0.f, px2 = 0.f;            // previous x (eps_old folded)
    float sg0 = 0.f, sg1 = 0.f, sg2 = 0.f;            // sigma (xx, yy, xy)
    float szz = 0.f, eqps = 0.f;

    const float4* xb = reinterpret_cast<const float4*>(x + (size_t)b * (kS * 3));
    float* op = out + (size_t)b * (kS * 3);

    // prefetch first block of 8 steps (24 floats = 6 float4)
    float4 buf[6], nbuf[6];
#pragma unroll
    for (int i = 0; i < 6; ++i) buf[i] = xb[i];

    for (int blk = 0; blk < kS / kT; ++blk) {
        // software-prefetch next block (independent of recurrence chain)
        if (blk + 1 < kS / kT) {
#pragma unroll
            for (int i = 0; i < 6; ++i) nbuf[i] = xb[(blk + 1) * 6 + i];
        }

        float xs[3 * kT];
#pragma unroll
        for (int i = 0; i < 6; ++i) {
            xs[4 * i + 0] = buf[i].x; xs[4 * i + 1] = buf[i].y;
            xs[4 * i + 2] = buf[i].z; xs[4 * i + 3] = buf[i].w;
        }

        float r[3 * kT];
#pragma unroll
        for (int t = 0; t < kT; ++t) {
            const float cx0 = xs[3 * t + 0];
            const float cx1 = xs[3 * t + 1];
            const float cx2 = xs[3 * t + 2];
            const float dx0 = cx0 - px0, dx1 = cx1 - px1, dx2 = cx2 - px2;
            px0 = cx0; px1 = cx1; px2 = cx2;

            const float t0 = sg0 + dx0 * e0[0] + dx1 * e0[1] + dx2 * e0[2];
            const float t1 = sg1 + dx0 * e1[0] + dx1 * e1[1] + dx2 * e1[2];
            const float t2 = sg2 + dx0 * e2[0] + dx1 * e2[1] + dx2 * e2[2];
            const float tz = szz + dx0 * lv[0] + dx1 * lv[1] + dx2 * lv[2];

            const float pm  = (t0 + t1 + tz) * (1.0f / 3.0f);
            const float dxx = t0 - pm, dyy = t1 - pm, dzz = tz - pm, dxy = t2;
            const float q2  = 1.5f * (dxx * dxx + dyy * dyy + dzz * dzz
                                      + 2.0f * dxy * dxy) + 1e-12f;
            const float q   = __builtin_amdgcn_sqrtf(q2);
            const float f   = q - (kSy0 + kH * eqps);
            const float dg  = (f > 0.0f) ? f * kInv3GH : 0.0f;
            const float fac = 1.0f - (3.0f * kG) * dg * __builtin_amdgcn_rcpf(q);

            sg0 = fmaf(fac, dxx, pm);
            sg1 = fmaf(fac, dyy, pm);
            sg2 = fac * dxy;
            szz = fmaf(fac, dzz, pm);
            eqps += dg;

            r[3 * t + 0] = sp[0][0] * sg0 + sp[0][1] * sg1 + sp[0][2] * sg2;
            r[3 * t + 1] = sp[1][0] * sg0 + sp[1][1] * sg1 + sp[1][2] * sg2;
            r[3 * t + 2] = sp[2][0] * sg0 + sp[2][1] * sg1 + sp[2][2] * sg2;
        }

        // batched 64-lane butterfly reduce: 24 independent values x 6 levels
#pragma unroll
        for (int m = 1; m < 64; m <<= 1)
#pragma unroll
            for (int v = 0; v < 3 * kT; ++v)
                r[v] += __shfl_xor(r[v], m, 64);

        if (k == 0) {
            float4* o4 = reinterpret_cast<float4*>(op + blk * (kT * 3));
#pragma unroll
            for (int i = 0; i < 6; ++i)
                o4[i] = make_float4(r[4 * i + 0], r[4 * i + 1],
                                    r[4 * i + 2], r[4 * i + 3]);
        }

#pragma unroll
        for (int i = 0; i < 6; ++i) buf[i] = nbuf[i];
    }
}

extern "C" void kernel_launch(void* const* d_in, const int* in_sizes, int n_in,
                              void* d_out, int out_size, void* d_ws, size_t ws_size,
                              hipStream_t stream) {
    const float* x  = (const float*)d_in[0];   // (128, 2048, 3)
    const float* W1 = (const float*)d_in[1];   // (192, 3)
    const float* W2 = (const float*)d_in[2];   // (3, 192)
    float* out = (float*)d_out;                // (128, 2048, 3)

    j2_scan_kernel<<<dim3(128), dim3(64), 0, stream>>>(x, W1, W2, out);
}

// Round 2
// 194.010 us; speedup vs baseline: 2.7867x; 2.7867x over previous
//
#include <hip/hip_runtime.h>
#include <cmath>

namespace {
constexpr float kE   = 3130.0f;
constexpr float kNu  = 0.37f;
constexpr float kSy0 = 64.8f;
constexpr float kH   = 100.0f;
constexpr float kG   = kE / (2.0f * (1.0f + kNu));
constexpr float kLam = kE * kNu / ((1.0f + kNu) * (1.0f - 2.0f * kNu));
constexpr float kC   = kE / ((1.0f + kNu) * (1.0f - 2.0f * kNu));
constexpr float kC11 = kC * (1.0f - kNu);
constexpr float kC12 = kC * kNu;
constexpr float kInv3GH = 1.0f / (3.0f * kG + kH);
constexpr float k3G  = 3.0f * kG;
constexpr int kS  = 2048;      // time steps
constexpr int kT  = 16;        // steps per block/phase
constexpr int kNB = kS / kT;   // 128 blocks
constexpr int kLs = 192;
}

// DPP-based wave64 sum; total lands in lane 63. VALU-only (no LDS latency).
template<int CTRL, int RM, int BM>
__device__ __forceinline__ float dppmov(float v) {
    return __int_as_float(
        __builtin_amdgcn_update_dpp(0, __float_as_int(v), CTRL, RM, BM, false));
}
__device__ __forceinline__ float wave_sum63(float v) {
    v += dppmov<0x111, 0xf, 0xf>(v);  // row_shr:1
    v += dppmov<0x112, 0xf, 0xf>(v);  // row_shr:2
    v += dppmov<0x114, 0xf, 0xf>(v);  // row_shr:4
    v += dppmov<0x118, 0xf, 0xf>(v);  // row_shr:8  -> lane15 of each row = rowsum
    v += dppmov<0x142, 0xa, 0xf>(v);  // row_bcast:15 -> rows 1,3
    v += dppmov<0x143, 0xc, 0xf>(v);  // row_bcast:31 -> rows 2,3; lane63 = total
    return v;
}

// Workgroup = 3 waves on one CU.
//   wave 0: sequential J2 scan (latency-bound chain only).
//   waves 1,2: strain projection u = E*dx (next block), output r = sp*sg +
//              DPP reduction + store (previous block). Split by half-block.
// Double-buffered LDS, one __syncthreads per 16-step block.
__global__ __launch_bounds__(192, 1)
void j2_pc_kernel(const float* __restrict__ x,
                  const float* __restrict__ W1,
                  const float* __restrict__ W2,
                  float* __restrict__ out)
{
    __shared__ float4 ubuf[2][kT][64];   // u0,u1,u2,uz per (t, lane)
    __shared__ float4 sgbuf[2][kT][64];  // sg0,sg1,sg2,- per (t, lane)

    const int b = blockIdx.x;        // 0..127
    const int w = threadIdx.x >> 6;  // wave id 0..2
    const int k = threadIdx.x & 63;  // lane

    const float* xb = x + (size_t)b * (kS * 3);
    float* ob = out + (size_t)b * (kS * 3);

    // ---- helper-wave per-lane constants ------------------------------------
    float e0[3], e1[3], e2[3], lv[3], sp[3][3];
    if (w != 0) {
        float wr[3][3];
#pragma unroll
        for (int j = 0; j < 3; ++j)
#pragma unroll
            for (int f = 0; f < 3; ++f)
                wr[j][f] = W1[(3 * k + j) * 3 + f];
#pragma unroll
        for (int f = 0; f < 3; ++f) {
            e0[f] = kC11 * wr[0][f] + kC12 * wr[1][f];
            e1[f] = kC12 * wr[0][f] + kC11 * wr[1][f];
            e2[f] = kG * wr[2][f];
            lv[f] = kLam * (wr[0][f] + wr[1][f]);
        }
#pragma unroll
        for (int o = 0; o < 3; ++o)
#pragma unroll
            for (int j = 0; j < 3; ++j) {
                float v = W2[o * kLs + 3 * k + j];
                sp[o][j] = log1pf(expf(v));
            }
    }

    // ---- scan state (wave 0) ----------------------------------------------
    float sg0 = 0.f, sg1 = 0.f, sg2 = 0.f, szz = 0.f;
    float y = kSy0;                       // running yield = SIGY0 + H*eqps
    const int tlo = (w == 2) ? 8 : 0;     // helper half-block

    // Phase schedule:
    //   helpers produce u for block p      at phase p      (p = 0..kNB-1)
    //   scan consumes block p-1            at phase p      (p = 1..kNB)
    //   helpers consume sg of block p-2    at phase p      (p = 2..kNB+1)
    for (int phase = 0; phase <= kNB + 1; ++phase) {
        if (w == 0) {
            if (phase >= 1 && phase <= kNB) {
                const int blk = phase - 1, pb = blk & 1;
                float4 u[kT];
#pragma unroll
                for (int t = 0; t < kT; ++t) u[t] = ubuf[pb][t][k];
#pragma unroll
                for (int t = 0; t < kT; ++t) {
                    const float t0 = sg0 + u[t].x;
                    const float t1 = sg1 + u[t].y;
                    const float t2 = sg2 + u[t].z;
                    const float tz = szz + u[t].w;
                    const float pm  = (t0 + t1 + tz) * (1.0f / 3.0f);
                    const float dxx = t0 - pm, dyy = t1 - pm, dzz = tz - pm;
                    const float sa  = fmaf(dxx, dxx, dyy * dyy);
                    const float sb  = fmaf(dzz, dzz, (2.0f * t2) * t2);
                    const float q2  = fmaf(1.5f, sa + sb, 1e-12f);
                    const float qq  = __builtin_amdgcn_sqrtf(q2);
                    const float rq  = __builtin_amdgcn_rcpf(qq);
                    const float f   = qq - y;
                    const float dg  = (f > 0.0f) ? f * kInv3GH : 0.0f;
                    y = fmaf(kH, dg, y);
                    const float fac = fmaf(-(k3G * dg), rq, 1.0f);
                    sg0 = fmaf(fac, dxx, pm);
                    sg1 = fmaf(fac, dyy, pm);
                    sg2 = fac * t2;
                    szz = fmaf(fac, dzz, pm);
                    sgbuf[pb][t][k] = make_float4(sg0, sg1, sg2, 0.f);
                }
            }
        } else {
            // ---- produce u for block `phase` (half-block tlo..tlo+7) ------
            if (phase < kNB) {
                const int p = phase, pb = p & 1;
                float xv[28];
                if (w == 1) {
                    if (p == 0) {
                        xv[0] = xv[1] = xv[2] = xv[3] = 0.f;  // x_{-1} = 0
                        const float4* s4 = reinterpret_cast<const float4*>(xb);
#pragma unroll
                        for (int i = 0; i < 6; ++i) {
                            float4 v = s4[i];
                            xv[4 + 4 * i] = v.x; xv[5 + 4 * i] = v.y;
                            xv[6 + 4 * i] = v.z; xv[7 + 4 * i] = v.w;
                        }
                    } else {
                        const float4* s4 =
                            reinterpret_cast<const float4*>(xb + p * 48 - 4);
#pragma unroll
                        for (int i = 0; i < 7; ++i) {
                            float4 v = s4[i];
                            xv[4 * i]     = v.x; xv[4 * i + 1] = v.y;
                            xv[4 * i + 2] = v.z; xv[4 * i + 3] = v.w;
                        }
                    }
                } else {
                    const float4* s4 =
                        reinterpret_cast<const float4*>(xb + p * 48 + 20);
#pragma unroll
                    for (int i = 0; i < 7; ++i) {
                        float4 v = s4[i];
                        xv[4 * i]     = v.x; xv[4 * i + 1] = v.y;
                        xv[4 * i + 2] = v.z; xv[4 * i + 3] = v.w;
                    }
                }
                // xv[3t+1..3t+3] = x_{s-1}, xv[3t+4..3t+6] = x_s
#pragma unroll
                for (int t = 0; t < 8; ++t) {
                    const float dx0 = xv[3 * t + 4] - xv[3 * t + 1];
                    const float dx1 = xv[3 * t + 5] - xv[3 * t + 2];
                    const float dx2 = xv[3 * t + 6] - xv[3 * t + 3];
                    float4 u;
                    u.x = fmaf(e0[0], dx0, fmaf(e0[1], dx1, e0[2] * dx2));
                    u.y = fmaf(e1[0], dx0, fmaf(e1[1], dx1, e1[2] * dx2));
                    u.z = fmaf(e2[0], dx0, fmaf(e2[1], dx1, e2[2] * dx2));
                    u.w = fmaf(lv[0], dx0, fmaf(lv[1], dx1, lv[2] * dx2));
                    ubuf[pb][tlo + t][k] = u;
                }
            }
            // ---- consume sg of block `phase-2`: r, reduce, store ----------
            if (phase >= 2) {
                const int q = phase - 2, qb = q & 1;
                float r[24];
#pragma unroll
                for (int t = 0; t < 8; ++t) {
                    float4 s = sgbuf[qb][tlo + t][k];
                    r[3 * t]     = fmaf(sp[0][0], s.x, fmaf(sp[0][1], s.y, sp[0][2] * s.z));
                    r[3 * t + 1] = fmaf(sp[1][0], s.x, fmaf(sp[1][1], s.y, sp[1][2] * s.z));
                    r[3 * t + 2] = fmaf(sp[2][0], s.x, fmaf(sp[2][1], s.y, sp[2][2] * s.z));
                }
#pragma unroll
                for (int v = 0; v < 24; ++v) r[v] = wave_sum63(r[v]);
                if (k == 63) {
                    float4* o4 = reinterpret_cast<float4*>(ob + q * 48 + tlo * 3);
#pragma unroll
                    for (int i = 0; i < 6; ++i)
                        o4[i] = make_float4(r[4 * i], r[4 * i + 1],
                                            r[4 * i + 2], r[4 * i + 3]);
                }
            }
        }
        __syncthreads();
    }
}

extern "C" void kernel_launch(void* const* d_in, const int* in_sizes, int n_in,
                              void* d_out, int out_size, void* d_ws, size_t ws_size,
                              hipStream_t stream) {
    const float* x  = (const float*)d_in[0];   // (128, 2048, 3)
    const float* W1 = (const float*)d_in[1];   // (192, 3)
    const float* W2 = (const float*)d_in[2];   // (3, 192)
    float* out = (float*)d_out;                // (128, 2048, 3)

    j2_pc_kernel<<<dim3(128), dim3(192), 0, stream>>>(x, W1, W2, out);
}